// Round 6
// baseline (1490.469 us; speedup 1.0000x reference)
//
#include <hip/hip_runtime.h>

// GAT encoder, B=8, N=1024, D=768, H=4. adj int32; float tensors bf16 OR f32,
// runtime-detected (flag in ws). Outputs: yy [B,N,D] then node_scores [B,N].
//
// DEEP-PAIR ROUND (base = round-5 at 1480 us):
//  * Wh1T double-buffered: A in ws, B in d_out yy[7] region (free until G4[7];
//    last Wh1T_B read G2[3,7] precedes it). G1[h]->Wh1T[h&1], G2[h] reads same.
//  * New schedule per batch: A1[0] solo; then per h: pair(G2[h], G1[next]) and
//    pair(G3[h], A1[h+1]); tail G33, A2, G4. 115 -> 91 dispatches; 21 attn
//    kernels now hide under G3 GEMMs.
//  * f1/f2: THREE 8KB buffers rotating (P in ws; Q,R fill d_out scores region
//    exactly). Writer t -> buf t%3. Zero-jobs ride G2-side block0 (zmask);
//    full writer/reader/zero timeline hand-verified incl. b=7 boundary.
//  * attn rewritten wave-per-row (4 rows/block, shfl-only, no LDS/barriers).
//
// ws (peak 6,824,192 B, unchanged): P f32[2048] @0, flag @8192,
//   Wh1T_A f16[768,1024] @8448, Wh2T @1581312, att f16[1024,1024] @3154176,
//   hout f16[1024,768] @5251328 (end 6,824,192).

typedef unsigned short ushortT;
typedef _Float16 f16;
typedef __attribute__((ext_vector_type(8))) _Float16 f16x8;
typedef __attribute__((ext_vector_type(4))) _Float16 f16x4;
typedef __attribute__((ext_vector_type(4))) float f32x4;
typedef __attribute__((ext_vector_type(2))) float f32x2;
typedef __attribute__((ext_vector_type(8))) unsigned short u16x8;
typedef __attribute__((ext_vector_type(2))) unsigned short u16x2;
typedef __attribute__((ext_vector_type(4))) int i32x4;

#define ALPHA 0.2f

__device__ __forceinline__ float b2f(ushortT u) {
  union { unsigned int i; float f; } c; c.i = ((unsigned int)u) << 16; return c.f;
}
__device__ __forceinline__ ushortT f2b(float f) {
  union { float f; unsigned int u; } c; c.f = f;
  unsigned int u = c.u;
  u += 0x7FFFu + ((u >> 16) & 1u);   // RNE
  return (ushortT)(u >> 16);
}
// Wh1T_B lives at the start of d_out's yy[7] region (flag-dependent layout).
__device__ __forceinline__ f16* whB(char* dout, int flg) {
  return (f16*)(dout + (flg ? 22020096L : 11010048L));
}
// f-buffers: 0 = P (ws), 1 = Q, 2 = R (d_out scores region, 8KB each).
__device__ __forceinline__ float* fbuf(int sel, float* Pws, char* dout, int flg) {
  if (sel == 0) return Pws;
  return (float*)(dout + (flg ? 25165824L : 12582912L) + (long)(sel - 1) * 8192);
}
__device__ __forceinline__ void gld16(const f16* g, f16* l) {
  __builtin_amdgcn_global_load_lds(
      (const __attribute__((address_space(1))) void*)g,
      (__attribute__((address_space(3))) void*)l, 16, 0, 0);
}

// ---- dtype detector; zeroes P, Q, R ----------------------------------------
__global__ void detect_dtype(const ushortT* __restrict__ X, int* __restrict__ flag,
                             float* __restrict__ Pws, char* __restrict__ dout) {
  __shared__ int s[256];
  int t = threadIdx.x, c = 0;
  for (int i = t; i < 16384; i += 256) {
    int e = (X[2 * i] >> 7) & 0xFF;
    if (e > 140 || e < 100) c++;     // genuine bf16 N(0,1): essentially never
  }
  s[t] = c; __syncthreads();
  for (int o = 128; o > 0; o >>= 1) { if (t < o) s[t] += s[t + o]; __syncthreads(); }
  __syncthreads();
  int fl = (s[0] > 1000) ? 1 : 0;    // 1 -> inputs are f32
  if (t == 0) *flag = fl;
  float* Qv = (float*)(dout + (fl ? 25165824L : 12582912L));
#pragma unroll
  for (int i = 0; i < 8; i++) Pws[t + i * 256] = 0.f;
#pragma unroll
  for (int i = 0; i < 16; i++) Qv[t + i * 256] = 0.f;
}

// ---- GEMM body: C[1024,768] = A[1024,K] @ B[K,768] --------------------------
struct GA {
  const void* A; const void* B; void* C; const void* R; const void* avec;
  long aOff, bOff, cOff, rOff, avOff;
  int K, lda, ldb, aRaw, accum, fd, fsel, zmask, bWhb, cWhb;
};

template <int MODE, int BSRC>
__device__ void gbody(const GA a, float* Pws, char* dout, int flg,
                      f16* AS, f16* BS, int n0, int m0, bool bid0) {
  int t = threadIdx.x;
  int aTy = a.aRaw ? (flg ? 2 : 1) : 0;   // 0 f16, 1 bf16, 2 f32
  float* fv = fbuf(a.fsel, Pws, dout, flg);
  const void* Bres = a.bWhb ? (const void*)whB(dout, flg) : a.B;
  void*       Cres = a.cWhb ? (void*)whB(dout, flg) : a.C;

  if (a.zmask && bid0) {
#pragma unroll
    for (int sb = 0; sb < 3; sb++)
      if ((a.zmask >> sb) & 1) {
        float* z = fbuf(sb, Pws, dout, flg);
#pragma unroll
        for (int i = 0; i < 8; i++) z[t + i * 256] = 0.f;
      }
  }

  const f16*     Ah = (const f16*)a.A;
  const ushortT* Au = (const ushortT*)a.A;
  const float*   Af = (const float*)a.A;
  const f16*     Bh = (const f16*)Bres;
  const ushortT* Bu = (const ushortT*)Bres;
  const float*   Bf = (const float*)Bres;

  // compute-side lane geometry
  int lane = t & 63, wid = t >> 6;
  int wr = wid >> 1, wc = wid & 1;            // 2x2 waves of 32x32
  int lr = lane & 15, lg = lane >> 4, l7 = lane & 7;
  int aRow0 = (wr * 32 + lr) * 64, aRow1 = aRow0 + 16 * 64;
  int bRow0 = (wc * 32 + lr) * 64, bRow1 = bRow0 + 16 * 64;
  int ch0 = ((lg) ^ l7) * 8, ch1 = ((4 + lg) ^ l7) * 8;

  f32x4 acc[2][2];
#pragma unroll
  for (int i = 0; i < 2; i++)
#pragma unroll
    for (int j = 0; j < 2; j++) acc[i][j] = (f32x4){0.f, 0.f, 0.f, 0.f};

  auto compute = [&](int cur) {
    f16* Ac = AS + cur * 4096; f16* Bc = BS + cur * 4096;
#pragma unroll
    for (int kk = 0; kk < 2; kk++) {
      int ch = kk ? ch1 : ch0;
      f16x8 a0 = *(const f16x8*)(Ac + aRow0 + ch);
      f16x8 a1 = *(const f16x8*)(Ac + aRow1 + ch);
      f16x8 b0 = *(const f16x8*)(Bc + bRow0 + ch);
      f16x8 b1 = *(const f16x8*)(Bc + bRow1 + ch);
      acc[0][0] = __builtin_amdgcn_mfma_f32_16x16x32_f16(a0, b0, acc[0][0], 0, 0, 0);
      acc[0][1] = __builtin_amdgcn_mfma_f32_16x16x32_f16(a0, b1, acc[0][1], 0, 0, 0);
      acc[1][0] = __builtin_amdgcn_mfma_f32_16x16x32_f16(a1, b0, acc[1][0], 0, 0, 0);
      acc[1][1] = __builtin_amdgcn_mfma_f32_16x16x32_f16(a1, b1, acc[1][1], 0, 0, 0);
    }
  };

  int KT = a.K >> 6;

  if (BSRC == 0) {
    // ---- global_load_lds staging: waves 0/1 -> A, waves 2/3 -> B ------------
    int gr = lane >> 3, gcn = lane & 7, swz = (gcn ^ (gr & 7)) * 8;
    int isB = wid >> 1, cq4 = (wid & 1) * 4;
    long gA = a.aOff + (long)(m0 + gr) * a.lda + swz;
    long gB = a.bOff + (long)(n0 + gr) * (long)a.K + swz;
    auto stageG = [&](int buf, int kt) {
      if (!isB) {
        const f16* g = Ah + gA + (long)kt * 64;
        f16* dst = AS + buf * 4096;
#pragma unroll
        for (int c = 0; c < 4; c++)
          gld16(g + (long)(cq4 + c) * 8 * a.lda, dst + (cq4 + c) * 512);
      } else {
        const f16* g = Bh + gB + (long)kt * 64;
        f16* dst = BS + buf * 4096;
#pragma unroll
        for (int c = 0; c < 4; c++)
          gld16(g + (long)(cq4 + c) * 8 * a.K, dst + (cq4 + c) * 512);
      }
    };
    stageG(0, 0);
    __syncthreads();
    for (int kt = 0; kt < KT; ++kt) {
      int cur = kt & 1;
      if (kt + 1 < KT) stageG(cur ^ 1, kt + 1);
      compute(cur);
      __syncthreads();
    }
  } else {
    // ---- register staging (proven path) -------------------------------------
    int tq = t >> 2, cq = t & 3;
    long aBase = a.aOff + (long)(m0 + tq) * a.lda + cq * 16;
    int stA0 = tq * 64 + (((2 * cq)     ^ (tq & 7)) * 8);
    int stA1 = tq * 64 + (((2 * cq + 1) ^ (tq & 7)) * 8);
    int q2 = t & 31, cB = t >> 5;
    int nb0 = 2 * q2, nb1 = nb0 + 1;
    int stB0 = nb0 * 64 + ((cB ^ (nb0 & 7)) * 8);
    int stB1 = nb1 * 64 + ((cB ^ (nb1 & 7)) * 8);

    f16x8 ra0, ra1, rb0, rb1;
    auto loadA = [&](int kt) {
      long g = aBase + (long)kt * 64;
      if (aTy == 0) {
        ra0 = *(const f16x8*)(Ah + g);
        ra1 = *(const f16x8*)(Ah + g + 8);
      } else if (aTy == 1) {
        u16x8 v0 = *(const u16x8*)(Au + g);
        u16x8 v1 = *(const u16x8*)(Au + g + 8);
#pragma unroll
        for (int j = 0; j < 8; j++) { ra0[j] = (f16)b2f(v0[j]); ra1[j] = (f16)b2f(v1[j]); }
      } else {
        f32x4 v0 = *(const f32x4*)(Af + g);
        f32x4 v1 = *(const f32x4*)(Af + g + 4);
        f32x4 v2 = *(const f32x4*)(Af + g + 8);
        f32x4 v3 = *(const f32x4*)(Af + g + 12);
#pragma unroll
        for (int j = 0; j < 4; j++) {
          ra0[j] = (f16)v0[j]; ra0[4 + j] = (f16)v1[j];
          ra1[j] = (f16)v2[j]; ra1[4 + j] = (f16)v3[j];
        }
      }
    };
    auto loadB = [&](int kt) {
      long rbase = a.bOff + (long)(kt * 64 + cB * 8) * a.ldb + n0 + 2 * q2;
      if (flg) {
#pragma unroll
        for (int j = 0; j < 8; j++) {
          f32x2 v = *(const f32x2*)(Bf + rbase + (long)j * a.ldb);
          rb0[j] = (f16)v[0]; rb1[j] = (f16)v[1];
        }
      } else {
#pragma unroll
        for (int j = 0; j < 8; j++) {
          u16x2 v = *(const u16x2*)(Bu + rbase + (long)j * a.ldb);
          rb0[j] = (f16)b2f(v[0]); rb1[j] = (f16)b2f(v[1]);
        }
      }
    };
    auto stage = [&](int buf) {
      *(f16x8*)(AS + buf * 4096 + stA0) = ra0;
      *(f16x8*)(AS + buf * 4096 + stA1) = ra1;
      *(f16x8*)(BS + buf * 4096 + stB0) = rb0;
      *(f16x8*)(BS + buf * 4096 + stB1) = rb1;
    };
    loadA(0); loadB(0);
    stage(0);
    loadA(1); loadB(1);
    __syncthreads();
    for (int kt = 0; kt < KT; ++kt) {
      int cur = kt & 1;
      if (kt + 1 < KT) stage(cur ^ 1);
      if (kt + 2 < KT) { loadA(kt + 2); loadB(kt + 2); }
      compute(cur);
      __syncthreads();
    }
  }

  // ---- epilogue: C frag mapping col = lane&15, row = 4*(lane>>4)+reg --------
  int rowb_base = m0 + wr * 32 + 4 * lg;
  int col_base  = n0 + wc * 32 + lr;

  float a1v[2], a2v[2];
  float p1[2][4], p2[2][4];
  if (a.fd) {
    const float* avf = (const float*)a.avec; const ushortT* avu = (const ushortT*)a.avec;
#pragma unroll
    for (int fn = 0; fn < 2; fn++) {
      int c = n0 + wc * 32 + fn * 16 + lr;
      a1v[fn] = flg ? avf[a.avOff + c]       : b2f(avu[a.avOff + c]);
      a2v[fn] = flg ? avf[a.avOff + 768 + c] : b2f(avu[a.avOff + 768 + c]);
    }
#pragma unroll
    for (int fm = 0; fm < 2; fm++)
#pragma unroll
      for (int r = 0; r < 4; r++) { p1[fm][r] = 0.f; p2[fm][r] = 0.f; }
  }

#pragma unroll
  for (int fm = 0; fm < 2; fm++) {
#pragma unroll
    for (int fn = 0; fn < 2; fn++) {
      int rowb = rowb_base + fm * 16;
      int col  = col_base + fn * 16;
      f32x4 v = acc[fm][fn];
      float fullv[4];
      if (MODE == 4) {                       // transposed plain store (Wh1T)
        f16x4 pk;
#pragma unroll
        for (int r = 0; r < 4; r++) { fullv[r] = v[r]; pk[r] = (f16)v[r]; }
        *(f16x4*)((f16*)Cres + (long)col * 1024 + rowb) = pk;
      } else if (MODE == 3) {                // transposed accumulate (Wh2T)
        f16* Cc = (f16*)Cres;
        long idx = (long)col * 1024 + rowb;
        f16x4 pk;
        if (a.accum) {
          f16x4 old = *(const f16x4*)(Cc + idx);
#pragma unroll
          for (int r = 0; r < 4; r++) { fullv[r] = (float)old[r] + v[r]; pk[r] = (f16)fullv[r]; }
        } else {
#pragma unroll
          for (int r = 0; r < 4; r++) { fullv[r] = v[r]; pk[r] = (f16)v[r]; }
        }
        *(f16x4*)(Cc + idx) = pk;
      } else {
#pragma unroll
        for (int r = 0; r < 4; r++) {
          int row = rowb + r;
          float x = v[r];
          x = x > 0.f ? x : __expf(x) - 1.f;   // elu (MODE 1 and 2)
          long ci = a.cOff + (long)row * 768 + col;
          if (MODE == 2) {
            long ri = a.rOff + (long)row * 768 + col;
            x += flg ? ((const float*)a.R)[ri] : b2f(((const ushortT*)a.R)[ri]);
            if (flg) ((float*)Cres)[ci] = x;
            else     ((ushortT*)Cres)[ci] = f2b(x);
          } else {
            ((f16*)Cres)[ci] = (f16)x;
          }
        }
      }
      if (a.fd) {
        float ac1 = a1v[fn], ac2 = a2v[fn];
#pragma unroll
        for (int r = 0; r < 4; r++) {
          p1[fm][r] += fullv[r] * ac1;
          p2[fm][r] += fullv[r] * ac2;
        }
      }
    }
  }

  if (a.fd) {
#pragma unroll
    for (int fm = 0; fm < 2; fm++)
#pragma unroll
      for (int r = 0; r < 4; r++) {
#pragma unroll
        for (int o = 1; o < 16; o <<= 1) {
          p1[fm][r] += __shfl_xor(p1[fm][r], o);
          p2[fm][r] += __shfl_xor(p2[fm][r], o);
        }
      }
    if (lr == 0) {
#pragma unroll
      for (int fm = 0; fm < 2; fm++)
#pragma unroll
        for (int r = 0; r < 4; r++) {
          int row = rowb_base + fm * 16 + r;
          atomicAdd(fv + row, p1[fm][r]);
          atomicAdd(fv + 1024 + row, p2[fm][r]);
        }
    }
  }
}

// ---- attn: wave-per-row masked softmax (no LDS, shfl-only) -------------------
__device__ void attn_body(const float* __restrict__ fvb, const int* __restrict__ adj,
                          f16* __restrict__ att, int rowBase) {
  int t = threadIdx.x, lane = t & 63, wid = t >> 6;
  int row = rowBase + wid;
  const float* f2 = fvb + 1024;
  const int* arow = adj + (size_t)row * 1024;
  f16* orow = att + (size_t)row * 1024;
  float f1i = fvb[row];
  int c0 = lane * 16;

  float e[16]; int msk[16];
  float mx = -1e38f;
#pragma unroll
  for (int g = 0; g < 4; g++) {
    i32x4 av = *(const i32x4*)(arow + c0 + g * 4);
    f32x4 fvv = *(const f32x4*)(f2 + c0 + g * 4);
#pragma unroll
    for (int c = 0; c < 4; c++) {
      float ev = f1i + fvv[c];
      ev = ev > 0.f ? ev : ALPHA * ev;
      e[g * 4 + c] = ev;
      msk[g * 4 + c] = av[c] > 0;
      if (msk[g * 4 + c]) mx = fmaxf(mx, ev);
    }
  }
#pragma unroll
  for (int o = 32; o > 0; o >>= 1) mx = fmaxf(mx, __shfl_xor(mx, o));
  bool none = mx < -1e37f;   // all-masked row -> reference softmax is uniform

  float sum = 0.f;
  float p[16];
#pragma unroll
  for (int i = 0; i < 16; i++) {
    p[i] = none ? 1.f : (msk[i] ? __expf(e[i] - mx) : 0.f);
    sum += p[i];
  }
#pragma unroll
  for (int o = 32; o > 0; o >>= 1) sum += __shfl_xor(sum, o);
  float inv = 1.f / sum;
  f16x8 o0, o1;
#pragma unroll
  for (int i = 0; i < 8; i++) { o0[i] = (f16)(p[i] * inv); o1[i] = (f16)(p[8 + i] * inv); }
  *(f16x8*)(orow + c0) = o0;
  *(f16x8*)(orow + c0 + 8) = o1;
}

// ---- kernels ----------------------------------------------------------------
template <int MODE, int BSRC>
__global__ __launch_bounds__(256) void k_solo(GA a, float* Pws, char* dout,
                                              const int* __restrict__ rflag) {
  __shared__ __align__(16) f16 As[2][4096];
  __shared__ __align__(16) f16 Bs[2][4096];
  gbody<MODE, BSRC>(a, Pws, dout, *rflag, &As[0][0], &Bs[0][0],
                    blockIdx.x * 64, blockIdx.y * 64,
                    blockIdx.x == 0 && blockIdx.y == 0);
}
// G2[h] (gload) || G1[next] (reg-staged); flat grid 384
__global__ __launch_bounds__(256) void k_pairGG(GA g2, GA g1, float* Pws, char* dout,
                                                const int* __restrict__ rflag) {
  __shared__ __align__(16) f16 As[2][4096];
  __shared__ __align__(16) f16 Bs[2][4096];
  int flg = *rflag;
  int id = blockIdx.x;
  if (id < 192)
    gbody<1, 0>(g2, Pws, dout, flg, &As[0][0], &Bs[0][0],
                (id % 12) * 64, (id / 12) * 64, id == 0);
  else {
    int l = id - 192;
    gbody<4, 1>(g1, Pws, dout, flg, &As[0][0], &Bs[0][0],
                (l % 12) * 64, (l / 12) * 64, false);
  }
}
// G3[h] || A1[h+1]; flat grid 448 (192 GEMM + 256 attn)
__global__ __launch_bounds__(256) void k_pairGA(GA g3, int rsel,
                                                const int* __restrict__ adj,
                                                f16* __restrict__ att,
                                                float* Pws, char* dout,
                                                const int* __restrict__ rflag) {
  __shared__ __align__(16) f16 As[2][4096];
  __shared__ __align__(16) f16 Bs[2][4096];
  int flg = *rflag;
  int id = blockIdx.x;
  if (id < 192)
    gbody<3, 1>(g3, Pws, dout, flg, &As[0][0], &Bs[0][0],
                (id % 12) * 64, (id / 12) * 64, id == 0);
  else
    attn_body(fbuf(rsel, Pws, dout, flg), adj, att, (id - 192) * 4);
}
__global__ __launch_bounds__(256) void k_attn(int rsel, const int* __restrict__ adj,
                                              f16* __restrict__ att,
                                              float* Pws, char* dout,
                                              const int* __restrict__ rflag) {
  int flg = *rflag;
  attn_body(fbuf(rsel, Pws, dout, flg), adj, att, blockIdx.x * 4);
}

// ---- classifier: scores[row] = sigmoid(yy[row]@w + b) * mask[row] ------------
__global__ __launch_bounds__(256) void cls_kernel(
    void* __restrict__ outbase, const void* __restrict__ w,
    const void* __restrict__ bc, const void* __restrict__ mask,
    const int* __restrict__ rflag) {
  int t = threadIdx.x, lane = t & 63, wv = t >> 6;
  long row = (long)blockIdx.x * 4 + wv;    // 0..8191
  int f32 = *rflag;
  const float* yf = (const float*)outbase; const ushortT* yu = (const ushortT*)outbase;
  const float* wf = (const float*)w;       const ushortT* wu = (const ushortT*)w;
  float s = 0.f;
  for (int d = lane; d < 768; d += 64) {
    float yv = f32 ? yf[row * 768 + d] : b2f(yu[row * 768 + d]);
    float wvv = f32 ? wf[d] : b2f(wu[d]);
    s += yv * wvv;
  }
#pragma unroll
  for (int o = 32; o > 0; o >>= 1) s += __shfl_down(s, o);
  if (lane == 0) {
    float bb = f32 ? ((const float*)bc)[0] : b2f(((const ushortT*)bc)[0]);
    float mk = f32 ? ((const float*)mask)[row] : b2f(((const ushortT*)mask)[row]);
    float sig = 1.f / (1.f + __expf(-(s + bb)));
    long oi = 6291456L + row;
    if (f32) ((float*)outbase)[oi] = sig * mk;
    else ((ushortT*)outbase)[oi] = f2b(sig * mk);
  }
}

extern "C" void kernel_launch(void* const* d_in, const int* in_sizes, int n_in,
                              void* d_out, int out_size, void* d_ws, size_t ws_size,
                              hipStream_t stream) {
  (void)in_sizes; (void)n_in; (void)out_size; (void)ws_size;

  const void* X    = d_in[0];               // [8,1024,768]
  const int*  adj  = (const int*)d_in[1];   // [8,1024,1024]
  const void* maskN= d_in[2];               // [8,1024]
  const void* Wh   = d_in[3];               // [4,768,768]
  const void* aH   = d_in[4];               // [4,1536]
  const void* Wo   = d_in[5];               // [3072,768]
  const void* aO   = d_in[6];               // [1536]
  const void* wcls = d_in[7];               // [768]
  const void* bcls = d_in[8];               // [1]

  char* ws = (char*)d_ws;
  float* Pws  = (float*)(ws + 0);           // f-buffer 0
  int*   flag = (int*)(ws + 8192);
  f16* Wh1A = (f16*)(ws + 8448);            // Wh1T buffer A [768,1024] f16
  f16* Wh2T = (f16*)(ws + 1581312);         // [768,1024] f16
  f16* attb = (f16*)(ws + 3154176);         // [1024,1024] f16
  f16* hout = (f16*)(ws + 5251328);         // [1024,768] f16; end 6,824,192
  char* dob = (char*)d_out;

  detect_dtype<<<1, 256, 0, stream>>>((const ushortT*)X, flag, Pws, dob);

  auto mkG1 = [&](int b, int h) {
    GA g{}; g.A = X; g.B = Wh; g.C = Wh1A; g.avec = aH;
    g.aOff = (long)b * 786432; g.bOff = (long)h * 589824;
    g.avOff = (long)h * 1536;
    g.K = 768; g.lda = 768; g.ldb = 768; g.aRaw = 1;
    g.fd = 1; g.cWhb = h & 1;
    return g;
  };
  auto mkG2 = [&](int h) {
    GA g{}; g.A = attb; g.B = Wh1A; g.C = hout;
    g.K = 1024; g.lda = 1024; g.ldb = 1024;
    g.bWhb = h & 1;
    return g;
  };
  auto mkG3 = [&](int h) {
    GA g{}; g.A = hout; g.B = Wo; g.C = Wh2T; g.avec = aO;
    g.bOff = (long)h * 589824;
    g.K = 768; g.lda = 768; g.ldb = 768;
    g.accum = h > 0 ? 1 : 0;
    return g;
  };

  dim3 gg(12, 16);
  int w = 0;
  auto wn = [&]() { int v = w % 3; ++w; return v; };

  // G1[0,0] solo (writer 0)
  int fsG10 = wn();
  {
    GA g1 = mkG1(0, 0); g1.fsel = fsG10;
    k_solo<4, 1><<<gg, 256, 0, stream>>>(g1, Pws, dob, flag);
  }

  for (int b = 0; b < 8; b++) {
    const int* adjb = adj + (size_t)b * 1048576;
    long xOff = (long)b * 786432;

    // D1: A1[0]
    k_attn<<<256, 256, 0, stream>>>(fsG10, adjb, attb, Pws, dob, flag);

    int lastFsel = 0;
    for (int h = 0; h < 4; h++) {
      GA g2 = mkG2(h);
      bool hasG1 = (h < 3) || (b < 7);
      if (hasG1) {
        int nh = (h < 3) ? h + 1 : 0;
        int nbb = (h < 3) ? b : b + 1;
        GA g1 = mkG1(nbb, nh);
        g1.fsel = wn();
        g2.zmask = (1 << (w % 3)) | ((h == 3) ? (1 << ((w + 1) % 3)) : 0);
        k_pairGG<<<dim3(384), 256, 0, stream>>>(g2, g1, Pws, dob, flag);
        if (nh == 0) fsG10 = g1.fsel;
        lastFsel = g1.fsel;
      } else {
        g2.zmask = (1 << (w % 3));           // buf for G33[7]
        k_solo<1, 0><<<gg, 256, 0, stream>>>(g2, Pws, dob, flag);
      }
      if (h < 3) {
        GA g3 = mkG3(h);
        k_pairGA<<<dim3(448), 256, 0, stream>>>(g3, lastFsel, adjb, attb,
                                                Pws, dob, flag);
      }
    }
    // D9: G33 (fused layer-2 fdot)
    GA g33 = mkG3(3); g33.fd = 1; g33.fsel = wn();
    k_solo<3, 1><<<gg, 256, 0, stream>>>(g33, Pws, dob, flag);
    // D10: A2
    k_attn<<<256, 256, 0, stream>>>(g33.fsel, adjb, attb, Pws, dob, flag);
    // D11: G4 -> yy[b]
    GA g4{}; g4.A = attb; g4.B = Wh2T; g4.C = d_out; g4.R = X;
    g4.cOff = xOff; g4.rOff = xOff;
    g4.K = 1024; g4.lda = 1024; g4.ldb = 1024;
    k_solo<2, 0><<<gg, 256, 0, stream>>>(g4, Pws, dob, flag);
  }

  cls_kernel<<<2048, 256, 0, stream>>>(d_out, wcls, bcls, maskN, flag);
}

// Round 7
// 1475.891 us; speedup vs baseline: 1.0099x; 1.0099x over previous
//
#include <hip/hip_runtime.h>

// GAT encoder, B=8, N=1024, D=768, H=4. adj int32; float tensors bf16 OR f32,
// runtime-detected (flag in ws). Outputs: yy [B,N,D] then node_scores [B,N].
//
// COUNTED-VMCNT ROUND (base = round-6 schedule at 1490 us, unchanged):
//  * The round-6 mainloops drained vmcnt(0) at every __syncthreads -> each
//    k-tile ate a full L2/HBM latency for the just-issued prefetch (measured
//    ~1900 cyc/k-tile vs ~400 floor). Fix per guide T3/T4:
//    - gload path (G2/G4): 4-deep LDS rotation (64KB), raw s_barrier, counted
//      s_waitcnt vmcnt(4) (never 0 mid-loop). Stage kt+2 || compute kt.
//    - reg path (G1/G3): 2-buffer schedule kept, __syncthreads replaced by
//      lgkmcnt(0)+s_barrier (no vmcnt drain; depth-2 register prefetch stays
//      in flight across the barrier).
//  * Everything else identical to round 6 (91 dispatches, Wh1T double-buffer,
//    3-way f-buffer rotation, wave-per-row attn, fused fdot epilogues).
//
// ws (peak 6,824,192 B, unchanged): P f32[2048] @0, flag @8192,
//   Wh1T_A f16[768,1024] @8448, Wh2T @1581312, att f16[1024,1024] @3154176,
//   hout f16[1024,768] @5251328 (end 6,824,192).

typedef unsigned short ushortT;
typedef _Float16 f16;
typedef __attribute__((ext_vector_type(8))) _Float16 f16x8;
typedef __attribute__((ext_vector_type(4))) _Float16 f16x4;
typedef __attribute__((ext_vector_type(4))) float f32x4;
typedef __attribute__((ext_vector_type(2))) float f32x2;
typedef __attribute__((ext_vector_type(8))) unsigned short u16x8;
typedef __attribute__((ext_vector_type(2))) unsigned short u16x2;
typedef __attribute__((ext_vector_type(4))) int i32x4;

#define ALPHA 0.2f

// fences: sched_barrier(0) after each asm keeps hipcc from hoisting LDS/MFMA
// ops across the waitcnt/barrier (guide rule 18).
#define VMCNT(n) do { asm volatile("s_waitcnt vmcnt(" #n ")" ::: "memory"); \
                      __builtin_amdgcn_sched_barrier(0); } while (0)
#define LGKM0()  do { asm volatile("s_waitcnt lgkmcnt(0)" ::: "memory"); \
                      __builtin_amdgcn_sched_barrier(0); } while (0)
#define BARRIER() do { __builtin_amdgcn_s_barrier(); \
                       __builtin_amdgcn_sched_barrier(0); } while (0)

__device__ __forceinline__ float b2f(ushortT u) {
  union { unsigned int i; float f; } c; c.i = ((unsigned int)u) << 16; return c.f;
}
__device__ __forceinline__ ushortT f2b(float f) {
  union { float f; unsigned int u; } c; c.f = f;
  unsigned int u = c.u;
  u += 0x7FFFu + ((u >> 16) & 1u);   // RNE
  return (ushortT)(u >> 16);
}
// Wh1T_B lives at the start of d_out's yy[7] region (flag-dependent layout).
__device__ __forceinline__ f16* whB(char* dout, int flg) {
  return (f16*)(dout + (flg ? 22020096L : 11010048L));
}
// f-buffers: 0 = P (ws), 1 = Q, 2 = R (d_out scores region, 8KB each).
__device__ __forceinline__ float* fbuf(int sel, float* Pws, char* dout, int flg) {
  if (sel == 0) return Pws;
  return (float*)(dout + (flg ? 25165824L : 12582912L) + (long)(sel - 1) * 8192);
}
__device__ __forceinline__ void gld16(const f16* g, f16* l) {
  __builtin_amdgcn_global_load_lds(
      (const __attribute__((address_space(1))) void*)g,
      (__attribute__((address_space(3))) void*)l, 16, 0, 0);
}

// ---- dtype detector; zeroes P, Q, R ----------------------------------------
__global__ void detect_dtype(const ushortT* __restrict__ X, int* __restrict__ flag,
                             float* __restrict__ Pws, char* __restrict__ dout) {
  __shared__ int s[256];
  int t = threadIdx.x, c = 0;
  for (int i = t; i < 16384; i += 256) {
    int e = (X[2 * i] >> 7) & 0xFF;
    if (e > 140 || e < 100) c++;     // genuine bf16 N(0,1): essentially never
  }
  s[t] = c; __syncthreads();
  for (int o = 128; o > 0; o >>= 1) { if (t < o) s[t] += s[t + o]; __syncthreads(); }
  __syncthreads();
  int fl = (s[0] > 1000) ? 1 : 0;    // 1 -> inputs are f32
  if (t == 0) *flag = fl;
  float* Qv = (float*)(dout + (fl ? 25165824L : 12582912L));
#pragma unroll
  for (int i = 0; i < 8; i++) Pws[t + i * 256] = 0.f;
#pragma unroll
  for (int i = 0; i < 16; i++) Qv[t + i * 256] = 0.f;
}

// ---- GEMM body: C[1024,768] = A[1024,K] @ B[K,768] --------------------------
struct GA {
  const void* A; const void* B; void* C; const void* R; const void* avec;
  long aOff, bOff, cOff, rOff, avOff;
  int K, lda, ldb, aRaw, accum, fd, fsel, zmask, bWhb, cWhb;
};

template <int MODE, int BSRC>
__device__ void gbody(const GA a, float* Pws, char* dout, int flg,
                      f16* AS, f16* BS, int n0, int m0, bool bid0) {
  int t = threadIdx.x;
  int aTy = a.aRaw ? (flg ? 2 : 1) : 0;   // 0 f16, 1 bf16, 2 f32
  float* fv = fbuf(a.fsel, Pws, dout, flg);
  const void* Bres = a.bWhb ? (const void*)whB(dout, flg) : a.B;
  void*       Cres = a.cWhb ? (void*)whB(dout, flg) : a.C;

  if (a.zmask && bid0) {
#pragma unroll
    for (int sb = 0; sb < 3; sb++)
      if ((a.zmask >> sb) & 1) {
        float* z = fbuf(sb, Pws, dout, flg);
#pragma unroll
        for (int i = 0; i < 8; i++) z[t + i * 256] = 0.f;
      }
  }

  const f16*     Ah = (const f16*)a.A;
  const ushortT* Au = (const ushortT*)a.A;
  const float*   Af = (const float*)a.A;
  const f16*     Bh = (const f16*)Bres;
  const ushortT* Bu = (const ushortT*)Bres;
  const float*   Bf = (const float*)Bres;

  // compute-side lane geometry
  int lane = t & 63, wid = t >> 6;
  int wr = wid >> 1, wc = wid & 1;            // 2x2 waves of 32x32
  int lr = lane & 15, lg = lane >> 4, l7 = lane & 7;
  int aRow0 = (wr * 32 + lr) * 64, aRow1 = aRow0 + 16 * 64;
  int bRow0 = (wc * 32 + lr) * 64, bRow1 = bRow0 + 16 * 64;
  int ch0 = ((lg) ^ l7) * 8, ch1 = ((4 + lg) ^ l7) * 8;

  f32x4 acc[2][2];
#pragma unroll
  for (int i = 0; i < 2; i++)
#pragma unroll
    for (int j = 0; j < 2; j++) acc[i][j] = (f32x4){0.f, 0.f, 0.f, 0.f};

  auto compute = [&](int buf) {
    f16* Ac = AS + buf * 4096; f16* Bc = BS + buf * 4096;
#pragma unroll
    for (int kk = 0; kk < 2; kk++) {
      int ch = kk ? ch1 : ch0;
      f16x8 a0 = *(const f16x8*)(Ac + aRow0 + ch);
      f16x8 a1 = *(const f16x8*)(Ac + aRow1 + ch);
      f16x8 b0 = *(const f16x8*)(Bc + bRow0 + ch);
      f16x8 b1 = *(const f16x8*)(Bc + bRow1 + ch);
      acc[0][0] = __builtin_amdgcn_mfma_f32_16x16x32_f16(a0, b0, acc[0][0], 0, 0, 0);
      acc[0][1] = __builtin_amdgcn_mfma_f32_16x16x32_f16(a0, b1, acc[0][1], 0, 0, 0);
      acc[1][0] = __builtin_amdgcn_mfma_f32_16x16x32_f16(a1, b0, acc[1][0], 0, 0, 0);
      acc[1][1] = __builtin_amdgcn_mfma_f32_16x16x32_f16(a1, b1, acc[1][1], 0, 0, 0);
    }
  };

  int KT = a.K >> 6;

  if (BSRC == 0) {
    // ---- gload staging, 4-deep rotation, counted vmcnt ----------------------
    // waves 0/1 -> A, waves 2/3 -> B; per wave per stage = 4 gld16 (vmcnt=4).
    int gr = lane >> 3, gcn = lane & 7, swz = (gcn ^ (gr & 7)) * 8;
    int isB = wid >> 1, cq4 = (wid & 1) * 4;
    long gA = a.aOff + (long)(m0 + gr) * a.lda + swz;
    long gB = a.bOff + (long)(n0 + gr) * (long)a.K + swz;
    auto stageG = [&](int buf, int kt) {
      if (!isB) {
        const f16* g = Ah + gA + (long)kt * 64;
        f16* dst = AS + buf * 4096;
#pragma unroll
        for (int c = 0; c < 4; c++)
          gld16(g + (long)(cq4 + c) * 8 * a.lda, dst + (cq4 + c) * 512);
      } else {
        const f16* g = Bh + gB + (long)kt * 64;
        f16* dst = BS + buf * 4096;
#pragma unroll
        for (int c = 0; c < 4; c++)
          gld16(g + (long)(cq4 + c) * 8 * a.K, dst + (cq4 + c) * 512);
      }
    };
    stageG(0, 0);
    stageG(1, 1);
    VMCNT(4);            // my S0 done (S1 in flight)
    BARRIER();           // everyone's S0 done
    for (int kt = 0; kt < KT; ++kt) {
      if (kt + 2 < KT) stageG((kt + 2) & 3, kt + 2);  // distinct from bufs kt-1,kt
      compute(kt & 3);
      if (kt + 1 < KT) {
        if (kt + 2 < KT) { VMCNT(4); } else { VMCNT(0); }  // drain S_{kt+1} only
        LGKM0();
        BARRIER();       // everyone's S_{kt+1} done; all past compute(kt)
      }
    }
  } else {
    // ---- register staging, 2 buffers; barrier WITHOUT vmcnt drain -----------
    int tq = t >> 2, cq = t & 3;
    long aBase = a.aOff + (long)(m0 + tq) * a.lda + cq * 16;
    int stA0 = tq * 64 + (((2 * cq)     ^ (tq & 7)) * 8);
    int stA1 = tq * 64 + (((2 * cq + 1) ^ (tq & 7)) * 8);
    int q2 = t & 31, cB = t >> 5;
    int nb0 = 2 * q2, nb1 = nb0 + 1;
    int stB0 = nb0 * 64 + ((cB ^ (nb0 & 7)) * 8);
    int stB1 = nb1 * 64 + ((cB ^ (nb1 & 7)) * 8);

    f16x8 ra0, ra1, rb0, rb1;
    auto loadA = [&](int kt) {
      long g = aBase + (long)kt * 64;
      if (aTy == 0) {
        ra0 = *(const f16x8*)(Ah + g);
        ra1 = *(const f16x8*)(Ah + g + 8);
      } else if (aTy == 1) {
        u16x8 v0 = *(const u16x8*)(Au + g);
        u16x8 v1 = *(const u16x8*)(Au + g + 8);
#pragma unroll
        for (int j = 0; j < 8; j++) { ra0[j] = (f16)b2f(v0[j]); ra1[j] = (f16)b2f(v1[j]); }
      } else {
        f32x4 v0 = *(const f32x4*)(Af + g);
        f32x4 v1 = *(const f32x4*)(Af + g + 4);
        f32x4 v2 = *(const f32x4*)(Af + g + 8);
        f32x4 v3 = *(const f32x4*)(Af + g + 12);
#pragma unroll
        for (int j = 0; j < 4; j++) {
          ra0[j] = (f16)v0[j]; ra0[4 + j] = (f16)v1[j];
          ra1[j] = (f16)v2[j]; ra1[4 + j] = (f16)v3[j];
        }
      }
    };
    auto loadB = [&](int kt) {
      long rbase = a.bOff + (long)(kt * 64 + cB * 8) * a.ldb + n0 + 2 * q2;
      if (flg) {
#pragma unroll
        for (int j = 0; j < 8; j++) {
          f32x2 v = *(const f32x2*)(Bf + rbase + (long)j * a.ldb);
          rb0[j] = (f16)v[0]; rb1[j] = (f16)v[1];
        }
      } else {
#pragma unroll
        for (int j = 0; j < 8; j++) {
          u16x2 v = *(const u16x2*)(Bu + rbase + (long)j * a.ldb);
          rb0[j] = (f16)b2f(v[0]); rb1[j] = (f16)b2f(v[1]);
        }
      }
    };
    auto stage = [&](int buf) {
      *(f16x8*)(AS + buf * 4096 + stA0) = ra0;
      *(f16x8*)(AS + buf * 4096 + stA1) = ra1;
      *(f16x8*)(BS + buf * 4096 + stB0) = rb0;
      *(f16x8*)(BS + buf * 4096 + stB1) = rb1;
    };
    loadA(0); loadB(0);
    stage(0);
    loadA(1); loadB(1);
    LGKM0();             // stage(0)'s ds_writes complete
    BARRIER();
    for (int kt = 0; kt < KT; ++kt) {
      int cur = kt & 1;
      if (kt + 1 < KT) stage(cur ^ 1);               // auto counted-vmcnt on regs
      if (kt + 2 < KT) { loadA(kt + 2); loadB(kt + 2); }  // stays in flight
      compute(cur);
      LGKM0();           // ds_writes visible; NO vmcnt drain
      BARRIER();
    }
  }

  // ---- epilogue: C frag mapping col = lane&15, row = 4*(lane>>4)+reg --------
  int rowb_base = m0 + wr * 32 + 4 * lg;
  int col_base  = n0 + wc * 32 + lr;

  float a1v[2], a2v[2];
  float p1[2][4], p2[2][4];
  if (a.fd) {
    const float* avf = (const float*)a.avec; const ushortT* avu = (const ushortT*)a.avec;
#pragma unroll
    for (int fn = 0; fn < 2; fn++) {
      int c = n0 + wc * 32 + fn * 16 + lr;
      a1v[fn] = flg ? avf[a.avOff + c]       : b2f(avu[a.avOff + c]);
      a2v[fn] = flg ? avf[a.avOff + 768 + c] : b2f(avu[a.avOff + 768 + c]);
    }
#pragma unroll
    for (int fm = 0; fm < 2; fm++)
#pragma unroll
      for (int r = 0; r < 4; r++) { p1[fm][r] = 0.f; p2[fm][r] = 0.f; }
  }

#pragma unroll
  for (int fm = 0; fm < 2; fm++) {
#pragma unroll
    for (int fn = 0; fn < 2; fn++) {
      int rowb = rowb_base + fm * 16;
      int col  = col_base + fn * 16;
      f32x4 v = acc[fm][fn];
      float fullv[4];
      if (MODE == 4) {                       // transposed plain store (Wh1T)
        f16x4 pk;
#pragma unroll
        for (int r = 0; r < 4; r++) { fullv[r] = v[r]; pk[r] = (f16)v[r]; }
        *(f16x4*)((f16*)Cres + (long)col * 1024 + rowb) = pk;
      } else if (MODE == 3) {                // transposed accumulate (Wh2T)
        f16* Cc = (f16*)Cres;
        long idx = (long)col * 1024 + rowb;
        f16x4 pk;
        if (a.accum) {
          f16x4 old = *(const f16x4*)(Cc + idx);
#pragma unroll
          for (int r = 0; r < 4; r++) { fullv[r] = (float)old[r] + v[r]; pk[r] = (f16)fullv[r]; }
        } else {
#pragma unroll
          for (int r = 0; r < 4; r++) { fullv[r] = v[r]; pk[r] = (f16)v[r]; }
        }
        *(f16x4*)(Cc + idx) = pk;
      } else {
#pragma unroll
        for (int r = 0; r < 4; r++) {
          int row = rowb + r;
          float x = v[r];
          x = x > 0.f ? x : __expf(x) - 1.f;   // elu (MODE 1 and 2)
          long ci = a.cOff + (long)row * 768 + col;
          if (MODE == 2) {
            long ri = a.rOff + (long)row * 768 + col;
            x += flg ? ((const float*)a.R)[ri] : b2f(((const ushortT*)a.R)[ri]);
            if (flg) ((float*)Cres)[ci] = x;
            else     ((ushortT*)Cres)[ci] = f2b(x);
          } else {
            ((f16*)Cres)[ci] = (f16)x;
          }
        }
      }
      if (a.fd) {
        float ac1 = a1v[fn], ac2 = a2v[fn];
#pragma unroll
        for (int r = 0; r < 4; r++) {
          p1[fm][r] += fullv[r] * ac1;
          p2[fm][r] += fullv[r] * ac2;
        }
      }
    }
  }

  if (a.fd) {
#pragma unroll
    for (int fm = 0; fm < 2; fm++)
#pragma unroll
      for (int r = 0; r < 4; r++) {
#pragma unroll
        for (int o = 1; o < 16; o <<= 1) {
          p1[fm][r] += __shfl_xor(p1[fm][r], o);
          p2[fm][r] += __shfl_xor(p2[fm][r], o);
        }
      }
    if (lr == 0) {
#pragma unroll
      for (int fm = 0; fm < 2; fm++)
#pragma unroll
        for (int r = 0; r < 4; r++) {
          int row = rowb_base + fm * 16 + r;
          atomicAdd(fv + row, p1[fm][r]);
          atomicAdd(fv + 1024 + row, p2[fm][r]);
        }
    }
  }
}

// ---- attn: wave-per-row masked softmax (no LDS, shfl-only) -------------------
__device__ void attn_body(const float* __restrict__ fvb, const int* __restrict__ adj,
                          f16* __restrict__ att, int rowBase) {
  int t = threadIdx.x, lane = t & 63, wid = t >> 6;
  int row = rowBase + wid;
  const float* f2 = fvb + 1024;
  const int* arow = adj + (size_t)row * 1024;
  f16* orow = att + (size_t)row * 1024;
  float f1i = fvb[row];
  int c0 = lane * 16;

  float e[16]; int msk[16];
  float mx = -1e38f;
#pragma unroll
  for (int g = 0; g < 4; g++) {
    i32x4 av = *(const i32x4*)(arow + c0 + g * 4);
    f32x4 fvv = *(const f32x4*)(f2 + c0 + g * 4);
#pragma unroll
    for (int c = 0; c < 4; c++) {
      float ev = f1i + fvv[c];
      ev = ev > 0.f ? ev : ALPHA * ev;
      e[g * 4 + c] = ev;
      msk[g * 4 + c] = av[c] > 0;
      if (msk[g * 4 + c]) mx = fmaxf(mx, ev);
    }
  }
#pragma unroll
  for (int o = 32; o > 0; o >>= 1) mx = fmaxf(mx, __shfl_xor(mx, o));
  bool none = mx < -1e37f;   // all-masked row -> reference softmax is uniform

  float sum = 0.f;
  float p[16];
#pragma unroll
  for (int i = 0; i < 16; i++) {
    p[i] = none ? 1.f : (msk[i] ? __expf(e[i] - mx) : 0.f);
    sum += p[i];
  }
#pragma unroll
  for (int o = 32; o > 0; o >>= 1) sum += __shfl_xor(sum, o);
  float inv = 1.f / sum;
  f16x8 o0, o1;
#pragma unroll
  for (int i = 0; i < 8; i++) { o0[i] = (f16)(p[i] * inv); o1[i] = (f16)(p[8 + i] * inv); }
  *(f16x8*)(orow + c0) = o0;
  *(f16x8*)(orow + c0 + 8) = o1;
}

// ---- kernels ----------------------------------------------------------------
template <int MODE, int BSRC>
__global__ __launch_bounds__(256) void k_solo(GA a, float* Pws, char* dout,
                                              const int* __restrict__ rflag) {
  __shared__ __align__(16) f16 As[4][4096];
  __shared__ __align__(16) f16 Bs[4][4096];
  gbody<MODE, BSRC>(a, Pws, dout, *rflag, &As[0][0], &Bs[0][0],
                    blockIdx.x * 64, blockIdx.y * 64,
                    blockIdx.x == 0 && blockIdx.y == 0);
}
// G2[h] (gload) || G1[next] (reg-staged); flat grid 384
__global__ __launch_bounds__(256) void k_pairGG(GA g2, GA g1, float* Pws, char* dout,
                                                const int* __restrict__ rflag) {
  __shared__ __align__(16) f16 As[4][4096];
  __shared__ __align__(16) f16 Bs[4][4096];
  int flg = *rflag;
  int id = blockIdx.x;
  if (id < 192)
    gbody<1, 0>(g2, Pws, dout, flg, &As[0][0], &Bs[0][0],
                (id % 12) * 64, (id / 12) * 64, id == 0);
  else {
    int l = id - 192;
    gbody<4, 1>(g1, Pws, dout, flg, &As[0][0], &Bs[0][0],
                (l % 12) * 64, (l / 12) * 64, false);
  }
}
// G3[h] || A1[h+1]; flat grid 448 (192 GEMM + 256 attn)
__global__ __launch_bounds__(256) void k_pairGA(GA g3, int rsel,
                                                const int* __restrict__ adj,
                                                f16* __restrict__ att,
                                                float* Pws, char* dout,
                                                const int* __restrict__ rflag) {
  __shared__ __align__(16) f16 As[4][4096];
  __shared__ __align__(16) f16 Bs[4][4096];
  int flg = *rflag;
  int id = blockIdx.x;
  if (id < 192)
    gbody<3, 1>(g3, Pws, dout, flg, &As[0][0], &Bs[0][0],
                (id % 12) * 64, (id / 12) * 64, id == 0);
  else
    attn_body(fbuf(rsel, Pws, dout, flg), adj, att, (id - 192) * 4);
}
__global__ __launch_bounds__(256) void k_attn(int rsel, const int* __restrict__ adj,
                                              f16* __restrict__ att,
                                              float* Pws, char* dout,
                                              const int* __restrict__ rflag) {
  int flg = *rflag;
  attn_body(fbuf(rsel, Pws, dout, flg), adj, att, blockIdx.x * 4);
}

// ---- classifier: scores[row] = sigmoid(yy[row]@w + b) * mask[row] ------------
__global__ __launch_bounds__(256) void cls_kernel(
    void* __restrict__ outbase, const void* __restrict__ w,
    const void* __restrict__ bc, const void* __restrict__ mask,
    const int* __restrict__ rflag) {
  int t = threadIdx.x, lane = t & 63, wv = t >> 6;
  long row = (long)blockIdx.x * 4 + wv;    // 0..8191
  int f32 = *rflag;
  const float* yf = (const float*)outbase; const ushortT* yu = (const ushortT*)outbase;
  const float* wf = (const float*)w;       const ushortT* wu = (const ushortT*)w;
  float s = 0.f;
  for (int d = lane; d < 768; d += 64) {
    float yv = f32 ? yf[row * 768 + d] : b2f(yu[row * 768 + d]);
    float wvv = f32 ? wf[d] : b2f(wu[d]);
    s += yv * wvv;
  }
#pragma unroll
  for (int o = 32; o > 0; o >>= 1) s += __shfl_down(s, o);
  if (lane == 0) {
    float bb = f32 ? ((const float*)bc)[0] : b2f(((const ushortT*)bc)[0]);
    float mk = f32 ? ((const float*)mask)[row] : b2f(((const ushortT*)mask)[row]);
    float sig = 1.f / (1.f + __expf(-(s + bb)));
    long oi = 6291456L + row;
    if (f32) ((float*)outbase)[oi] = sig * mk;
    else ((ushortT*)outbase)[oi] = f2b(sig * mk);
  }
}

extern "C" void kernel_launch(void* const* d_in, const int* in_sizes, int n_in,
                              void* d_out, int out_size, void* d_ws, size_t ws_size,
                              hipStream_t stream) {
  (void)in_sizes; (void)n_in; (void)out_size; (void)ws_size;

  const void* X    = d_in[0];               // [8,1024,768]
  const int*  adj  = (const int*)d_in[1];   // [8,1024,1024]
  const void* maskN= d_in[2];               // [8,1024]
  const void* Wh   = d_in[3];               // [4,768,768]
  const void* aH   = d_in[4];               // [4,1536]
  const void* Wo   = d_in[5];               // [3072,768]
  const void* aO   = d_in[6];               // [1536]
  const void* wcls = d_in[7];               // [768]
  const void* bcls = d_in[8];               // [1]

  char* ws = (char*)d_ws;
  float* Pws  = (float*)(ws + 0);           // f-buffer 0
  int*   flag = (int*)(ws + 8192);
  f16* Wh1A = (f16*)(ws + 8448);            // Wh1T buffer A [768,1024] f16
  f16* Wh2T = (f16*)(ws + 1581312);         // [768,1024] f16
  f16* attb = (f16*)(ws + 3154176);         // [1024,1024] f16
  f16* hout = (f16*)(ws + 5251328);         // [1024,768] f16; end 6,824,192
  char* dob = (char*)d_out;

  detect_dtype<<<1, 256, 0, stream>>>((const ushortT*)X, flag, Pws, dob);

  auto mkG1 = [&](int b, int h) {
    GA g{}; g.A = X; g.B = Wh; g.C = Wh1A; g.avec = aH;
    g.aOff = (long)b * 786432; g.bOff = (long)h * 589824;
    g.avOff = (long)h * 1536;
    g.K = 768; g.lda = 768; g.ldb = 768; g.aRaw = 1;
    g.fd = 1; g.cWhb = h & 1;
    return g;
  };
  auto mkG2 = [&](int h) {
    GA g{}; g.A = attb; g.B = Wh1A; g.C = hout;
    g.K = 1024; g.lda = 1024; g.ldb = 1024;
    g.bWhb = h & 1;
    return g;
  };
  auto mkG3 = [&](int h) {
    GA g{}; g.A = hout; g.B = Wo; g.C = Wh2T; g.avec = aO;
    g.bOff = (long)h * 589824;
    g.K = 768; g.lda = 768; g.ldb = 768;
    g.accum = h > 0 ? 1 : 0;
    return g;
  };

  dim3 gg(12, 16);
  int w = 0;
  auto wn = [&]() { int v = w % 3; ++w; return v; };

  // G1[0,0] solo (writer 0)
  int fsG10 = wn();
  {
    GA g1 = mkG1(0, 0); g1.fsel = fsG10;
    k_solo<4, 1><<<gg, 256, 0, stream>>>(g1, Pws, dob, flag);
  }

  for (int b = 0; b < 8; b++) {
    const int* adjb = adj + (size_t)b * 1048576;
    long xOff = (long)b * 786432;

    // D1: A1[0]
    k_attn<<<256, 256, 0, stream>>>(fsG10, adjb, attb, Pws, dob, flag);

    int lastFsel = 0;
    for (int h = 0; h < 4; h++) {
      GA g2 = mkG2(h);
      bool hasG1 = (h < 3) || (b < 7);
      if (hasG1) {
        int nh = (h < 3) ? h + 1 : 0;
        int nbb = (h < 3) ? b : b + 1;
        GA g1 = mkG1(nbb, nh);
        g1.fsel = wn();
        g2.zmask = (1 << (w % 3)) | ((h == 3) ? (1 << ((w + 1) % 3)) : 0);
        k_pairGG<<<dim3(384), 256, 0, stream>>>(g2, g1, Pws, dob, flag);
        if (nh == 0) fsG10 = g1.fsel;
        lastFsel = g1.fsel;
      } else {
        g2.zmask = (1 << (w % 3));           // buf for G33[7]
        k_solo<1, 0><<<gg, 256, 0, stream>>>(g2, Pws, dob, flag);
      }
      if (h < 3) {
        GA g3 = mkG3(h);
        k_pairGA<<<dim3(448), 256, 0, stream>>>(g3, lastFsel, adjb, attb,
                                                Pws, dob, flag);
      }
    }
    // D9: G33 (fused layer-2 fdot)
    GA g33 = mkG3(3); g33.fd = 1; g33.fsel = wn();
    k_solo<3, 1><<<gg, 256, 0, stream>>>(g33, Pws, dob, flag);
    // D10: A2
    k_attn<<<256, 256, 0, stream>>>(g33.fsel, adjb, attb, Pws, dob, flag);
    // D11: G4 -> yy[b]
    GA g4{}; g4.A = attb; g4.B = Wh2T; g4.C = d_out; g4.R = X;
    g4.cOff = xOff; g4.rOff = xOff;
    g4.K = 1024; g4.lda = 1024; g4.ldb = 1024;
    k_solo<2, 0><<<gg, 256, 0, stream>>>(g4, Pws, dob, flag);
  }

  cls_kernel<<<2048, 256, 0, stream>>>(d_out, wcls, bcls, maskN, flag);
}